// Round 7
// baseline (355.389 us; speedup 1.0000x reference)
//
#include <hip/hip_runtime.h>
#include <cstdint>

#define KT 9408      // K_TOTAL
#define NT 256       // o-tile per block (partial gemm)

// ---------------------------------------------------------------------------
// Partial GEMM:  partial[s][b][o] = sum_{k in split s} X[b,k] * W[o,k]
// Dual-source concatenated K (K1 then K2). M = 32 fixed. 256 threads.
// Per-thread tile 8b x 4o (acc = 32 VGPRs). Template KCV = staged k-chunk.
// KCV=32: 8 lanes cover one W row's 128B -> full-line fetches.
// Caller guarantees (K1+K2) % ksplit == 0, ((K1+K2)/ksplit) % KCV == 0,
// and K1 % KCV == 0 (so chunks/float4s never straddle the source boundary).
// Register prefetch (WF4 float4 + XS floats) hides HBM under the FMA block.
// ---------------------------------------------------------------------------
template <int KCV>
__global__ __launch_bounds__(256, 1) void gemm32_partial(
    const float* __restrict__ X1, const float* __restrict__ W1, int K1,
    const float* __restrict__ X2, const float* __restrict__ W2, int K2,
    float* __restrict__ partial, int O, int ksplit)
{
    __shared__ float Xs[KCV][32];        // [k_local][b]   (reads are broadcast)
    __shared__ float Wt[KCV][NT + 1];    // [k_local][o_local], pad -> ~2-way writes

    constexpr int LPR = KCV / 4;         // lanes per W row (4 or 8)
    constexpr int WF4 = NT * KCV / 1024; // float4 per thread (4 or 8)
    constexpr int XS  = KCV / 8;         // X scalars per thread (2 or 4)

    const int t      = threadIdx.x;
    const int o0     = blockIdx.x * NT;
    const int s      = blockIdx.y;
    const int kchunk = (K1 + K2) / ksplit;
    const int kbeg   = s * kchunk;
    const int kend   = kbeg + kchunk;
    const int lane   = t & 63;
    const int wv     = t >> 6;           // wave id -> b-group (8 b's)

    float4 wpre[WF4];
    float  xpre[XS];

    auto loadW = [&](int kc0) {
#pragma unroll
        for (int p = 0; p < WF4; ++p) {
            int f  = p * 256 + t;
            int r  = f / LPR;
            int c4 = (f % LPR) * 4;
            int o  = o0 + r;
            int kg = kc0 + c4;
            float4 v = make_float4(0.f, 0.f, 0.f, 0.f);
            if (o < O)
                v = (kg < K1) ? *(const float4*)&W1[(size_t)o * K1 + kg]
                              : *(const float4*)&W2[(size_t)o * K2 + (kg - K1)];
            wpre[p] = v;
        }
    };
    auto loadX = [&](int kc0) {
#pragma unroll
        for (int i = 0; i < XS; ++i) {
            int idx = t + 256 * i;
            int kg  = kc0 + (idx >> 5);
            int bb  = idx & 31;
            xpre[i] = (kg < K1) ? X1[(size_t)bb * K1 + kg]
                                : X2[(size_t)bb * K2 + (kg - K1)];
        }
    };

    loadW(kbeg);
    loadX(kbeg);

    float acc[8][4];
#pragma unroll
    for (int bi = 0; bi < 8; bi++)
#pragma unroll
        for (int j = 0; j < 4; j++) acc[bi][j] = 0.f;

    for (int kc0 = kbeg; kc0 < kend; kc0 += KCV) {
        // ---- commit prefetched regs to LDS
#pragma unroll
        for (int i = 0; i < XS; ++i) {
            int idx = t + 256 * i;
            Xs[idx >> 5][idx & 31] = xpre[i];
        }
#pragma unroll
        for (int p = 0; p < WF4; ++p) {
            int f  = p * 256 + t;
            int r  = f / LPR;
            int c4 = (f % LPR) * 4;
            Wt[c4 + 0][r] = wpre[p].x;
            Wt[c4 + 1][r] = wpre[p].y;
            Wt[c4 + 2][r] = wpre[p].z;
            Wt[c4 + 3][r] = wpre[p].w;
        }
        __syncthreads();

        // ---- issue next chunk's loads; they fly during the FMA block
        if (kc0 + KCV < kend) { loadW(kc0 + KCV); loadX(kc0 + KCV); }

        // ---- compute: KCV k-steps x (8b x 4o) FMAs
#pragma unroll
        for (int c = 0; c < KCV; c++) {
            float4 xa = *(const float4*)&Xs[c][wv * 8];       // wave-broadcast
            float4 xb = *(const float4*)&Xs[c][wv * 8 + 4];
            float xv[8] = {xa.x, xa.y, xa.z, xa.w, xb.x, xb.y, xb.z, xb.w};
            float ww[4];
#pragma unroll
            for (int j = 0; j < 4; j++) ww[j] = Wt[c][lane + 64 * j];
#pragma unroll
            for (int bi = 0; bi < 8; bi++)
#pragma unroll
                for (int j = 0; j < 4; j++) acc[bi][j] += xv[bi] * ww[j];
        }
        __syncthreads();
    }

    // ---- store partials (coalesced over o)
#pragma unroll
    for (int bi = 0; bi < 8; bi++) {
        int b = wv * 8 + bi;
#pragma unroll
        for (int j = 0; j < 4; j++) {
            int o = o0 + lane + 64 * j;
            if (o < O)
                partial[((size_t)s * 32 + b) * O + o] = acc[bi][j];
        }
    }
}

// ---------------------------------------------------------------------------
// Reduce K-split partials + bias(es) + optional ReLU.  Y is [32][O] row-major.
// ---------------------------------------------------------------------------
__global__ __launch_bounds__(256) void reduce_bias(
    const float* __restrict__ partial, const float* __restrict__ bias1,
    const float* __restrict__ bias2, float* __restrict__ Y, int O, int relu,
    int ksplit)
{
    int idx = blockIdx.x * 256 + threadIdx.x;
    if (idx >= 32 * O) return;
    int b = idx / O, o = idx - b * O;
    float s = bias1[o] + (bias2 ? bias2[o] : 0.f);
    for (int k = 0; k < ksplit; k++)
        s += partial[((size_t)k * 32 + b) * O + o];
    Y[idx] = relu ? fmaxf(s, 0.f) : s;
}

// ---------------------------------------------------------------------------
// MFMA conv chain. D-frag layout == B-frag layout (m89-verified), so each
// layer's output packs straight into the next layer's B operand — zero LDS.
// This round: TPW=8 with 1024 blocks (higher occupancy) + next-tile x
// prefetch so the 8 strided loads hide under the 18-MFMA chain.
// ---------------------------------------------------------------------------
typedef __attribute__((ext_vector_type(8))) short bf16x8;
typedef __attribute__((ext_vector_type(4))) float f32x4;

__device__ inline uint32_t pkbf(float lo, float hi) {   // 2 f32 -> packed bf16x2 (RNE)
    uint32_t a = __builtin_bit_cast(uint32_t, lo);
    uint32_t b = __builtin_bit_cast(uint32_t, hi);
    a = (a + 0x7FFFu + ((a >> 16) & 1u)) >> 16;
    b = (b + 0x7FFFu + ((b >> 16) & 1u)) & 0xFFFF0000u;
    return a | b;
}

#define MFMA16(a, b, c) __builtin_amdgcn_mfma_f32_16x16x32_bf16(a, b, c, 0, 0, 0)

#define TPW 8    // pixel tiles (16 px) per wave

__global__ __launch_bounds__(256, 3) void conv_mfma(
    const float* __restrict__ x, const float* __restrict__ ks,
    float* __restrict__ out)
{
    const int t  = threadIdx.x;
    const int b  = blockIdx.y;
    const int l  = t & 63;
    const int g  = l >> 4;         // lane group 0..3
    const int n  = l & 15;         // col (pixel-in-tile) / A row offset
    const int wid = blockIdx.x * 4 + (t >> 6);   // wave id in sample, 0..127

    const float* __restrict__ kb = ks + (size_t)b * KT;

    auto loadA = [&](const float* W, int ldw, int row0, int k0) -> bf16x8 {
        const float* p = W + (size_t)(row0 + n) * ldw + k0 + 4 * g;
        float4 lo = *(const float4*)p;
        float4 hi = *(const float4*)(p + 16);
        union { bf16x8 v; uint32_t u[4]; } r;
        r.u[0] = pkbf(lo.x, lo.y);
        r.u[1] = pkbf(lo.z, lo.w);
        r.u[2] = pkbf(hi.x, hi.y);
        r.u[3] = pkbf(hi.z, hi.w);
        return r.v;
    };
    auto loadBias = [&](int off) -> f32x4 {
        float4 v = *(const float4*)&kb[off + 4 * g];
        f32x4 r; r[0] = v.x; r[1] = v.y; r[2] = v.z; r[3] = v.w;
        return r;
    };

    bf16x8 ain[4], amid[4][2], aout[2][2], ashort[2];
#pragma unroll
    for (int rt = 0; rt < 4; ++rt) ain[rt] = loadA(kb, 32, 16 * rt, 0);
#pragma unroll
    for (int ot = 0; ot < 4; ++ot)
#pragma unroll
        for (int kf = 0; kf < 2; ++kf) amid[ot][kf] = loadA(kb + 2048, 64, 16 * ot, 32 * kf);
#pragma unroll
    for (int ot = 0; ot < 2; ++ot)
#pragma unroll
        for (int kf = 0; kf < 2; ++kf) aout[ot][kf] = loadA(kb + 6144, 64, 16 * ot, 32 * kf);
#pragma unroll
    for (int ot = 0; ot < 2; ++ot) ashort[ot] = loadA(kb + 8192, 32, 16 * ot, 0);

    f32x4 bin[4], bmid[4], bos[2];
#pragma unroll
    for (int rt = 0; rt < 4; ++rt) bin[rt] = loadBias(9216 + 16 * rt);
#pragma unroll
    for (int ot = 0; ot < 4; ++ot) bmid[ot] = loadBias(9280 + 16 * ot);
#pragma unroll
    for (int ot = 0; ot < 2; ++ot) {
        f32x4 a = loadBias(9344 + 16 * ot);   // b_out
        f32x4 c = loadBias(9376 + 16 * ot);   // b_short
#pragma unroll
        for (int r = 0; r < 4; ++r) a[r] += c[r];
        bos[ot] = a;
    }

    const float* __restrict__ xbase = x + (size_t)b * 524288 + (size_t)(4 * g) * 16384 + n;
    float* __restrict__ obase = out + (size_t)b * 524288 + (size_t)(4 * g) * 16384 + n;

    float e[8];
    auto loadx = [&](int px0) {
        const float* p = xbase + px0;
        e[0] = p[0]; e[1] = p[16384]; e[2] = p[2 * 16384]; e[3] = p[3 * 16384];
        const float* q = p + (size_t)16 * 16384;
        e[4] = q[0]; e[5] = q[16384]; e[6] = q[2 * 16384]; e[7] = q[3 * 16384];
    };
    loadx(wid * TPW * 16);

#pragma unroll 1
    for (int it = 0; it < TPW; ++it) {
        const int px0 = (wid * TPW + it) * 16;

        union { bf16x8 v; uint32_t u[4]; } bx;
        bx.u[0] = pkbf(e[0], e[1]); bx.u[1] = pkbf(e[2], e[3]);
        bx.u[2] = pkbf(e[4], e[5]); bx.u[3] = pkbf(e[6], e[7]);

        if (it + 1 < TPW) loadx(px0 + 16);   // prefetch next tile under MFMAs

        f32x4 h[4];
#pragma unroll
        for (int rt = 0; rt < 4; ++rt) {
            f32x4 acc = MFMA16(ain[rt], bx.v, bin[rt]);
#pragma unroll
            for (int r = 0; r < 4; ++r) acc[r] = fmaxf(acc[r], 0.f);
            h[rt] = acc;
        }
        union { bf16x8 v; uint32_t u[4]; } hb0, hb1;
        hb0.u[0] = pkbf(h[0][0], h[0][1]); hb0.u[1] = pkbf(h[0][2], h[0][3]);
        hb0.u[2] = pkbf(h[1][0], h[1][1]); hb0.u[3] = pkbf(h[1][2], h[1][3]);
        hb1.u[0] = pkbf(h[2][0], h[2][1]); hb1.u[1] = pkbf(h[2][2], h[2][3]);
        hb1.u[2] = pkbf(h[3][0], h[3][1]); hb1.u[3] = pkbf(h[3][2], h[3][3]);

        f32x4 m[4];
#pragma unroll
        for (int ot = 0; ot < 4; ++ot) {
            f32x4 acc = MFMA16(amid[ot][0], hb0.v, bmid[ot]);
            acc = MFMA16(amid[ot][1], hb1.v, acc);
#pragma unroll
            for (int r = 0; r < 4; ++r) acc[r] = fmaxf(acc[r], 0.f);
            m[ot] = acc;
        }
        union { bf16x8 v; uint32_t u[4]; } mb0, mb1;
        mb0.u[0] = pkbf(m[0][0], m[0][1]); mb0.u[1] = pkbf(m[0][2], m[0][3]);
        mb0.u[2] = pkbf(m[1][0], m[1][1]); mb0.u[3] = pkbf(m[1][2], m[1][3]);
        mb1.u[0] = pkbf(m[2][0], m[2][1]); mb1.u[1] = pkbf(m[2][2], m[2][3]);
        mb1.u[2] = pkbf(m[3][0], m[3][1]); mb1.u[3] = pkbf(m[3][2], m[3][3]);

#pragma unroll
        for (int ot = 0; ot < 2; ++ot) {
            f32x4 acc = MFMA16(ashort[ot], bx.v, bos[ot]);
            acc = MFMA16(aout[ot][0], mb0.v, acc);
            acc = MFMA16(aout[ot][1], mb1.v, acc);
            float* po = obase + (size_t)(16 * ot) * 16384 + px0;
            po[0]         = acc[0];
            po[16384]     = acc[1];
            po[2 * 16384] = acc[2];
            po[3 * 16384] = acc[3];
        }
    }
}

// ---------------------------------------------------------------------------
extern "C" void kernel_launch(void* const* d_in, const int* in_sizes, int n_in,
                              void* d_out, int out_size, void* d_ws, size_t ws_size,
                              hipStream_t stream)
{
    const float* x   = (const float*)d_in[0];
    const float* lat = (const float*)d_in[1];
    const float* w0  = (const float*)d_in[2];
    const float* b0  = (const float*)d_in[3];
    const float* w1a = (const float*)d_in[4];
    const float* b1a = (const float*)d_in[5];
    const float* w1b = (const float*)d_in[6];
    const float* b1b = (const float*)d_in[7];
    const float* w1s = (const float*)d_in[8];
    const float* b1s = (const float*)d_in[9];
    const float* w2a = (const float*)d_in[10];
    const float* b2a = (const float*)d_in[11];
    const float* w2b = (const float*)d_in[12];
    const float* b2b = (const float*)d_in[13];
    const float* w2s = (const float*)d_in[14];
    const float* b2s = (const float*)d_in[15];
    const float* wfa = (const float*)d_in[16];
    const float* bfa = (const float*)d_in[17];

    // intermediates in d_ws (~2.8 MB)
    float* ws  = (float*)d_ws;
    float* h0  = ws;               // 32*512
    float* t1  = ws + 16384;       // 32*1024
    float* h1  = ws + 49152;       // 32*512
    float* t2  = ws + 65536;       // 32*1024
    float* h2  = ws + 98304;       // 32*9408
    float* ksb = ws + 399360;      // 32*9408
    // K-split partials live in d_out (<=28.9 MB < 64 MB); conv overwrites at end.
    float* pbuf = (float*)d_out;

    dim3 blk(256);
    auto rg = [](int O) { return dim3((unsigned)((32 * O + 255) / 256)); };

    // h0 = lat @ w0.T + b0                      (K=512, KC16, split 32)
    gemm32_partial<16><<<dim3(2, 32), blk, 0, stream>>>(lat, w0, 512, nullptr, nullptr, 0, pbuf, 512, 32);
    reduce_bias<<<rg(512), blk, 0, stream>>>(pbuf, b0, nullptr, h0, 512, 0, 32);
    // t1 = relu(h0 @ w1a.T + b1a)               (K=512)
    gemm32_partial<16><<<dim3(4, 32), blk, 0, stream>>>(h0, w1a, 512, nullptr, nullptr, 0, pbuf, 1024, 32);
    reduce_bias<<<rg(1024), blk, 0, stream>>>(pbuf, b1a, nullptr, t1, 1024, 1, 32);
    // h1 = h0 @ w1s.T + b1s + t1 @ w1b.T + b1b  (K=1536, KC16, split 32 -> chunk 48)
    gemm32_partial<16><<<dim3(2, 32), blk, 0, stream>>>(h0, w1s, 512, t1, w1b, 1024, pbuf, 512, 32);
    reduce_bias<<<rg(512), blk, 0, stream>>>(pbuf, b1s, b1b, h1, 512, 0, 32);
    // t2 = relu(h1 @ w2a.T + b2a)               (K=512)
    gemm32_partial<16><<<dim3(4, 32), blk, 0, stream>>>(h1, w2a, 512, nullptr, nullptr, 0, pbuf, 1024, 32);
    reduce_bias<<<rg(1024), blk, 0, stream>>>(pbuf, b2a, nullptr, t2, 1024, 1, 32);
    // h2 = h1 @ w2s.T + b2s + t2 @ w2b.T + b2b  (K=1536, KC32, split 24 -> chunk 64)
    gemm32_partial<32><<<dim3(37, 24), blk, 0, stream>>>(h1, w2s, 512, t2, w2b, 1024, pbuf, KT, 24);
    reduce_bias<<<rg(KT), blk, 0, stream>>>(pbuf, b2s, b2b, h2, KT, 0, 24);
    // ks = h2 @ wfa.T + bfa                     (K=9408, KC32, split 21 -> chunk 448)
    gemm32_partial<32><<<dim3(37, 21), blk, 0, stream>>>(h2, wfa, KT, nullptr, nullptr, 0, pbuf, KT, 21);
    reduce_bias<<<rg(KT), blk, 0, stream>>>(pbuf, bfa, nullptr, ksb, KT, 0, 21);

    // MFMA conv chain: 1024 blocks, 8 tiles/wave
    conv_mfma<<<dim3(32, 32), blk, 0, stream>>>(x, ksb, (float*)d_out);
}

// Round 8
// 299.061 us; speedup vs baseline: 1.1884x; 1.1884x over previous
//
#include <hip/hip_runtime.h>
#include <cstdint>

#define KT 9408      // K_TOTAL
#define NT 256       // o-tile per block
#define KC 16        // k sub-chunk staged in LDS

// ---------------------------------------------------------------------------
// Partial GEMM:  partial[s][b][o] = sum_{k in split s} X[b,k] * W[o,k]
// Dual-source: concatenated K = K1 (X1,W1) then K2 (X2,W2). M = 32 fixed.
// Block: 256 threads. Per-thread tile 8b x 4o (acc = 32 VGPRs, no spills).
// EXACT R5 version (measured-best hypernet) — do not touch.
// ---------------------------------------------------------------------------
__global__ __launch_bounds__(256, 1) void gemm32_partial(
    const float* __restrict__ X1, const float* __restrict__ W1, int K1,
    const float* __restrict__ X2, const float* __restrict__ W2, int K2,
    float* __restrict__ partial, int O, int ksplit)
{
    __shared__ float Xs[KC][32];     // [k_local][b]
    __shared__ float Wt[KC][NT];     // [k_local][o_local] transposed

    const int t      = threadIdx.x;
    const int o0     = blockIdx.x * NT;
    const int s      = blockIdx.y;
    const int kchunk = (K1 + K2) / ksplit;     // multiple of KC
    const int kbeg   = s * kchunk;
    const int kend   = kbeg + kchunk;
    const int lane   = t & 63;
    const int wv     = t >> 6;                 // wave id -> b-group (8 b's)

    const int sr  = t >> 2;                    // 0..63  (+64*p)
    const int sc4 = (t & 3) << 2;              // 0,4,8,12

    float4 wpre[4];
    float  xpre[2];

    {
        int kc0 = kbeg;
#pragma unroll
        for (int p = 0; p < 4; ++p) {
            int r = sr + 64 * p;
            int o = o0 + r;
            int kg = kc0 + sc4;
            float4 v = make_float4(0.f, 0.f, 0.f, 0.f);
            if (o < O)
                v = (kg < K1) ? *(const float4*)&W1[(size_t)o * K1 + kg]
                              : *(const float4*)&W2[(size_t)o * K2 + (kg - K1)];
            wpre[p] = v;
        }
#pragma unroll
        for (int it = 0; it < 2; ++it) {
            int idx = t + 256 * it;
            int kg  = kc0 + (idx >> 5);
            int bb  = idx & 31;
            xpre[it] = (kg < K1) ? X1[(size_t)bb * K1 + kg]
                                 : X2[(size_t)bb * K2 + (kg - K1)];
        }
    }

    float acc[8][4];
#pragma unroll
    for (int bi = 0; bi < 8; bi++)
#pragma unroll
        for (int j = 0; j < 4; j++) acc[bi][j] = 0.f;

    for (int kc0 = kbeg; kc0 < kend; kc0 += KC) {
#pragma unroll
        for (int it = 0; it < 2; ++it) {
            int idx = t + 256 * it;
            Xs[idx >> 5][idx & 31] = xpre[it];
        }
#pragma unroll
        for (int p = 0; p < 4; ++p) {
            int r = sr + 64 * p;
            Wt[sc4 + 0][r] = wpre[p].x;
            Wt[sc4 + 1][r] = wpre[p].y;
            Wt[sc4 + 2][r] = wpre[p].z;
            Wt[sc4 + 3][r] = wpre[p].w;
        }
        __syncthreads();

        if (kc0 + KC < kend) {
            int kn = kc0 + KC;
#pragma unroll
            for (int p = 0; p < 4; ++p) {
                int r = sr + 64 * p;
                int o = o0 + r;
                int kg = kn + sc4;
                float4 v = make_float4(0.f, 0.f, 0.f, 0.f);
                if (o < O)
                    v = (kg < K1) ? *(const float4*)&W1[(size_t)o * K1 + kg]
                                  : *(const float4*)&W2[(size_t)o * K2 + (kg - K1)];
                wpre[p] = v;
            }
#pragma unroll
            for (int it = 0; it < 2; ++it) {
                int idx = t + 256 * it;
                int kg  = kn + (idx >> 5);
                int bb  = idx & 31;
                xpre[it] = (kg < K1) ? X1[(size_t)bb * K1 + kg]
                                     : X2[(size_t)bb * K2 + (kg - K1)];
            }
        }

#pragma unroll
        for (int c = 0; c < KC; c++) {
            float4 xa = *(const float4*)&Xs[c][wv * 8];       // wave-broadcast
            float4 xb = *(const float4*)&Xs[c][wv * 8 + 4];
            float xv[8] = {xa.x, xa.y, xa.z, xa.w, xb.x, xb.y, xb.z, xb.w};
            float w[4];
#pragma unroll
            for (int j = 0; j < 4; j++) w[j] = Wt[c][lane + 64 * j];
#pragma unroll
            for (int bi = 0; bi < 8; bi++)
#pragma unroll
                for (int j = 0; j < 4; j++) acc[bi][j] += xv[bi] * w[j];
        }
        __syncthreads();
    }

#pragma unroll
    for (int bi = 0; bi < 8; bi++) {
        int b = wv * 8 + bi;
#pragma unroll
        for (int j = 0; j < 4; j++) {
            int o = o0 + lane + 64 * j;
            if (o < O)
                partial[((size_t)s * 32 + b) * O + o] = acc[bi][j];
        }
    }
}

// ---------------------------------------------------------------------------
__global__ __launch_bounds__(256) void reduce_bias(
    const float* __restrict__ partial, const float* __restrict__ bias1,
    const float* __restrict__ bias2, float* __restrict__ Y, int O, int relu,
    int ksplit)
{
    int idx = blockIdx.x * 256 + threadIdx.x;
    if (idx >= 32 * O) return;
    int b = idx / O, o = idx - b * O;
    float s = bias1[o] + (bias2 ? bias2[o] : 0.f);
    for (int k = 0; k < ksplit; k++)
        s += partial[((size_t)k * 32 + b) * O + o];
    Y[idx] = relu ? fmaxf(s, 0.f) : s;
}

// ---------------------------------------------------------------------------
// MFMA conv chain. D-frag layout == B-frag layout (m89-verified), so each
// layer's output packs straight into the next layer's B operand — zero LDS.
// R8 change (the ONLY change vs R5): software-pipelined x loads.
//  - first tile's 8 loads issued BEFORE the weight/bias preamble
//  - next tile's loads issued right after the current B-frag pack, so the
//    ~600cy HBM round trip hides under the 18-MFMA + pack chain.
// TPW=16, grid (16,32) exactly as R5.
// ---------------------------------------------------------------------------
typedef __attribute__((ext_vector_type(8))) short bf16x8;
typedef __attribute__((ext_vector_type(4))) float f32x4;

__device__ inline uint32_t pkbf(float lo, float hi) {   // 2 f32 -> packed bf16x2 (RNE)
    uint32_t a = __builtin_bit_cast(uint32_t, lo);
    uint32_t b = __builtin_bit_cast(uint32_t, hi);
    a = (a + 0x7FFFu + ((a >> 16) & 1u)) >> 16;
    b = (b + 0x7FFFu + ((b >> 16) & 1u)) & 0xFFFF0000u;
    return a | b;
}

#define MFMA16(a, b, c) __builtin_amdgcn_mfma_f32_16x16x32_bf16(a, b, c, 0, 0, 0)

#define TPW 16   // pixel tiles (16 px) per wave

__global__ __launch_bounds__(256, 3) void conv_mfma(
    const float* __restrict__ x, const float* __restrict__ ks,
    float* __restrict__ out)
{
    const int t  = threadIdx.x;
    const int b  = blockIdx.y;
    const int l  = t & 63;
    const int g  = l >> 4;         // lane group 0..3
    const int n  = l & 15;         // col (pixel-in-tile) / A row offset
    const int wid = blockIdx.x * 4 + (t >> 6);   // wave id in sample, 0..63

    const float* __restrict__ kb = ks + (size_t)b * KT;
    const float* __restrict__ xbase = x + (size_t)b * 524288 + (size_t)(4 * g) * 16384 + n;
    float* __restrict__ obase = out + (size_t)b * 524288 + (size_t)(4 * g) * 16384 + n;

    // ---- issue first x-tile loads NOW; latency hides under weight setup
    float e[8];
    auto loadx = [&](int px0) {
        const float* p = xbase + px0;
        e[0] = p[0]; e[1] = p[16384]; e[2] = p[2 * 16384]; e[3] = p[3 * 16384];
        const float* q = p + (size_t)16 * 16384;
        e[4] = q[0]; e[5] = q[16384]; e[6] = q[2 * 16384]; e[7] = q[3 * 16384];
    };
    loadx(wid * TPW * 16);

    auto loadA = [&](const float* W, int ldw, int row0, int k0) -> bf16x8 {
        const float* p = W + (size_t)(row0 + n) * ldw + k0 + 4 * g;
        float4 lo = *(const float4*)p;
        float4 hi = *(const float4*)(p + 16);
        union { bf16x8 v; uint32_t u[4]; } r;
        r.u[0] = pkbf(lo.x, lo.y);
        r.u[1] = pkbf(lo.z, lo.w);
        r.u[2] = pkbf(hi.x, hi.y);
        r.u[3] = pkbf(hi.z, hi.w);
        return r.v;
    };
    auto loadBias = [&](int off) -> f32x4 {
        float4 v = *(const float4*)&kb[off + 4 * g];
        f32x4 r; r[0] = v.x; r[1] = v.y; r[2] = v.z; r[3] = v.w;
        return r;
    };

    bf16x8 ain[4], amid[4][2], aout[2][2], ashort[2];
#pragma unroll
    for (int rt = 0; rt < 4; ++rt) ain[rt] = loadA(kb, 32, 16 * rt, 0);
#pragma unroll
    for (int ot = 0; ot < 4; ++ot)
#pragma unroll
        for (int kf = 0; kf < 2; ++kf) amid[ot][kf] = loadA(kb + 2048, 64, 16 * ot, 32 * kf);
#pragma unroll
    for (int ot = 0; ot < 2; ++ot)
#pragma unroll
        for (int kf = 0; kf < 2; ++kf) aout[ot][kf] = loadA(kb + 6144, 64, 16 * ot, 32 * kf);
#pragma unroll
    for (int ot = 0; ot < 2; ++ot) ashort[ot] = loadA(kb + 8192, 32, 16 * ot, 0);

    f32x4 bin[4], bmid[4], bos[2];
#pragma unroll
    for (int rt = 0; rt < 4; ++rt) bin[rt] = loadBias(9216 + 16 * rt);
#pragma unroll
    for (int ot = 0; ot < 4; ++ot) bmid[ot] = loadBias(9280 + 16 * ot);
#pragma unroll
    for (int ot = 0; ot < 2; ++ot) {
        f32x4 a = loadBias(9344 + 16 * ot);   // b_out
        f32x4 c = loadBias(9376 + 16 * ot);   // b_short
#pragma unroll
        for (int r = 0; r < 4; ++r) a[r] += c[r];
        bos[ot] = a;
    }

#pragma unroll 1
    for (int it = 0; it < TPW; ++it) {
        const int px0 = (wid * TPW + it) * 16;

        // ---- pack current B-frag, then immediately issue next tile's loads
        union { bf16x8 v; uint32_t u[4]; } bx;
        bx.u[0] = pkbf(e[0], e[1]); bx.u[1] = pkbf(e[2], e[3]);
        bx.u[2] = pkbf(e[4], e[5]); bx.u[3] = pkbf(e[6], e[7]);

        if (it + 1 < TPW) loadx(px0 + 16);   // flies under the MFMA chain

        f32x4 h[4];
#pragma unroll
        for (int rt = 0; rt < 4; ++rt) {
            f32x4 acc = MFMA16(ain[rt], bx.v, bin[rt]);
#pragma unroll
            for (int r = 0; r < 4; ++r) acc[r] = fmaxf(acc[r], 0.f);
            h[rt] = acc;
        }
        union { bf16x8 v; uint32_t u[4]; } hb0, hb1;
        hb0.u[0] = pkbf(h[0][0], h[0][1]); hb0.u[1] = pkbf(h[0][2], h[0][3]);
        hb0.u[2] = pkbf(h[1][0], h[1][1]); hb0.u[3] = pkbf(h[1][2], h[1][3]);
        hb1.u[0] = pkbf(h[2][0], h[2][1]); hb1.u[1] = pkbf(h[2][2], h[2][3]);
        hb1.u[2] = pkbf(h[3][0], h[3][1]); hb1.u[3] = pkbf(h[3][2], h[3][3]);

        f32x4 m[4];
#pragma unroll
        for (int ot = 0; ot < 4; ++ot) {
            f32x4 acc = MFMA16(amid[ot][0], hb0.v, bmid[ot]);
            acc = MFMA16(amid[ot][1], hb1.v, acc);
#pragma unroll
            for (int r = 0; r < 4; ++r) acc[r] = fmaxf(acc[r], 0.f);
            m[ot] = acc;
        }
        union { bf16x8 v; uint32_t u[4]; } mb0, mb1;
        mb0.u[0] = pkbf(m[0][0], m[0][1]); mb0.u[1] = pkbf(m[0][2], m[0][3]);
        mb0.u[2] = pkbf(m[1][0], m[1][1]); mb0.u[3] = pkbf(m[1][2], m[1][3]);
        mb1.u[0] = pkbf(m[2][0], m[2][1]); mb1.u[1] = pkbf(m[2][2], m[2][3]);
        mb1.u[2] = pkbf(m[3][0], m[3][1]); mb1.u[3] = pkbf(m[3][2], m[3][3]);

#pragma unroll
        for (int ot = 0; ot < 2; ++ot) {
            f32x4 acc = MFMA16(ashort[ot], bx.v, bos[ot]);
            acc = MFMA16(aout[ot][0], mb0.v, acc);
            acc = MFMA16(aout[ot][1], mb1.v, acc);
            float* po = obase + (size_t)(16 * ot) * 16384 + px0;
            po[0]         = acc[0];
            po[16384]     = acc[1];
            po[2 * 16384] = acc[2];
            po[3 * 16384] = acc[3];
        }
    }
}

// ---------------------------------------------------------------------------
extern "C" void kernel_launch(void* const* d_in, const int* in_sizes, int n_in,
                              void* d_out, int out_size, void* d_ws, size_t ws_size,
                              hipStream_t stream)
{
    const float* x   = (const float*)d_in[0];
    const float* lat = (const float*)d_in[1];
    const float* w0  = (const float*)d_in[2];
    const float* b0  = (const float*)d_in[3];
    const float* w1a = (const float*)d_in[4];
    const float* b1a = (const float*)d_in[5];
    const float* w1b = (const float*)d_in[6];
    const float* b1b = (const float*)d_in[7];
    const float* w1s = (const float*)d_in[8];
    const float* b1s = (const float*)d_in[9];
    const float* w2a = (const float*)d_in[10];
    const float* b2a = (const float*)d_in[11];
    const float* w2b = (const float*)d_in[12];
    const float* b2b = (const float*)d_in[13];
    const float* w2s = (const float*)d_in[14];
    const float* b2s = (const float*)d_in[15];
    const float* wfa = (const float*)d_in[16];
    const float* bfa = (const float*)d_in[17];

    // intermediates in d_ws (~2.8 MB)
    float* ws  = (float*)d_ws;
    float* h0  = ws;               // 32*512
    float* t1  = ws + 16384;       // 32*1024
    float* h1  = ws + 49152;       // 32*512
    float* t2  = ws + 65536;       // 32*1024
    float* h2  = ws + 98304;       // 32*9408
    float* ksb = ws + 399360;      // 32*9408
    // K-split partials live in d_out (<=38.6 MB < 64 MB); conv overwrites at end.
    float* pbuf = (float*)d_out;

    dim3 blk(256);
    auto g  = [](int O, int ks) { return dim3((unsigned)((O + NT - 1) / NT), (unsigned)ks); };
    auto rg = [](int O) { return dim3((unsigned)((32 * O + 255) / 256)); };

    gemm32_partial<<<g(512, 32), blk, 0, stream>>>(lat, w0, 512, nullptr, nullptr, 0, pbuf, 512, 32);
    reduce_bias<<<rg(512), blk, 0, stream>>>(pbuf, b0, nullptr, h0, 512, 0, 32);
    gemm32_partial<<<g(1024, 32), blk, 0, stream>>>(h0, w1a, 512, nullptr, nullptr, 0, pbuf, 1024, 32);
    reduce_bias<<<rg(1024), blk, 0, stream>>>(pbuf, b1a, nullptr, t1, 1024, 1, 32);
    gemm32_partial<<<g(512, 32), blk, 0, stream>>>(h0, w1s, 512, t1, w1b, 1024, pbuf, 512, 32);
    reduce_bias<<<rg(512), blk, 0, stream>>>(pbuf, b1s, b1b, h1, 512, 0, 32);
    gemm32_partial<<<g(1024, 32), blk, 0, stream>>>(h1, w2a, 512, nullptr, nullptr, 0, pbuf, 1024, 32);
    reduce_bias<<<rg(1024), blk, 0, stream>>>(pbuf, b2a, nullptr, t2, 1024, 1, 32);
    gemm32_partial<<<g(KT, 32), blk, 0, stream>>>(h1, w2s, 512, t2, w2b, 1024, pbuf, KT, 32);
    reduce_bias<<<rg(KT), blk, 0, stream>>>(pbuf, b2s, b2b, h2, KT, 0, 32);
    gemm32_partial<<<g(KT, 28), blk, 0, stream>>>(h2, wfa, KT, nullptr, nullptr, 0, pbuf, KT, 28);
    reduce_bias<<<rg(KT), blk, 0, stream>>>(pbuf, bfa, nullptr, ksb, KT, 0, 28);

    // MFMA conv chain: grid (16 px-blocks, 32 samples), 4 waves/block, 16 tiles/wave
    conv_mfma<<<dim3(16, 32), blk, 0, stream>>>(x, ksb, (float*)d_out);
}

// Round 9
// 294.336 us; speedup vs baseline: 1.2074x; 1.0161x over previous
//
#include <hip/hip_runtime.h>
#include <cstdint>

#define KT 9408      // K_TOTAL
#define NT 256       // o-tile per block
#define KC 16        // k sub-chunk staged in LDS

// ---------------------------------------------------------------------------
// f32 partial GEMM (R5-exact) — used for the four small layers only.
// ---------------------------------------------------------------------------
__global__ __launch_bounds__(256, 1) void gemm32_partial(
    const float* __restrict__ X1, const float* __restrict__ W1, int K1,
    const float* __restrict__ X2, const float* __restrict__ W2, int K2,
    float* __restrict__ partial, int O, int ksplit)
{
    __shared__ float Xs[KC][32];     // [k_local][b]
    __shared__ float Wt[KC][NT];     // [k_local][o_local] transposed

    const int t      = threadIdx.x;
    const int o0     = blockIdx.x * NT;
    const int s      = blockIdx.y;
    const int kchunk = (K1 + K2) / ksplit;     // multiple of KC
    const int kbeg   = s * kchunk;
    const int kend   = kbeg + kchunk;
    const int lane   = t & 63;
    const int wv     = t >> 6;                 // wave id -> b-group (8 b's)

    const int sr  = t >> 2;                    // 0..63  (+64*p)
    const int sc4 = (t & 3) << 2;              // 0,4,8,12

    float4 wpre[4];
    float  xpre[2];

    {
        int kc0 = kbeg;
#pragma unroll
        for (int p = 0; p < 4; ++p) {
            int r = sr + 64 * p;
            int o = o0 + r;
            int kg = kc0 + sc4;
            float4 v = make_float4(0.f, 0.f, 0.f, 0.f);
            if (o < O)
                v = (kg < K1) ? *(const float4*)&W1[(size_t)o * K1 + kg]
                              : *(const float4*)&W2[(size_t)o * K2 + (kg - K1)];
            wpre[p] = v;
        }
#pragma unroll
        for (int it = 0; it < 2; ++it) {
            int idx = t + 256 * it;
            int kg  = kc0 + (idx >> 5);
            int bb  = idx & 31;
            xpre[it] = (kg < K1) ? X1[(size_t)bb * K1 + kg]
                                 : X2[(size_t)bb * K2 + (kg - K1)];
        }
    }

    float acc[8][4];
#pragma unroll
    for (int bi = 0; bi < 8; bi++)
#pragma unroll
        for (int j = 0; j < 4; j++) acc[bi][j] = 0.f;

    for (int kc0 = kbeg; kc0 < kend; kc0 += KC) {
#pragma unroll
        for (int it = 0; it < 2; ++it) {
            int idx = t + 256 * it;
            Xs[idx >> 5][idx & 31] = xpre[it];
        }
#pragma unroll
        for (int p = 0; p < 4; ++p) {
            int r = sr + 64 * p;
            Wt[sc4 + 0][r] = wpre[p].x;
            Wt[sc4 + 1][r] = wpre[p].y;
            Wt[sc4 + 2][r] = wpre[p].z;
            Wt[sc4 + 3][r] = wpre[p].w;
        }
        __syncthreads();

        if (kc0 + KC < kend) {
            int kn = kc0 + KC;
#pragma unroll
            for (int p = 0; p < 4; ++p) {
                int r = sr + 64 * p;
                int o = o0 + r;
                int kg = kn + sc4;
                float4 v = make_float4(0.f, 0.f, 0.f, 0.f);
                if (o < O)
                    v = (kg < K1) ? *(const float4*)&W1[(size_t)o * K1 + kg]
                                  : *(const float4*)&W2[(size_t)o * K2 + (kg - K1)];
                wpre[p] = v;
            }
#pragma unroll
            for (int it = 0; it < 2; ++it) {
                int idx = t + 256 * it;
                int kg  = kn + (idx >> 5);
                int bb  = idx & 31;
                xpre[it] = (kg < K1) ? X1[(size_t)bb * K1 + kg]
                                     : X2[(size_t)bb * K2 + (kg - K1)];
            }
        }

#pragma unroll
        for (int c = 0; c < KC; c++) {
            float4 xa = *(const float4*)&Xs[c][wv * 8];       // wave-broadcast
            float4 xb = *(const float4*)&Xs[c][wv * 8 + 4];
            float xv[8] = {xa.x, xa.y, xa.z, xa.w, xb.x, xb.y, xb.z, xb.w};
            float w[4];
#pragma unroll
            for (int j = 0; j < 4; j++) w[j] = Wt[c][lane + 64 * j];
#pragma unroll
            for (int bi = 0; bi < 8; bi++)
#pragma unroll
                for (int j = 0; j < 4; j++) acc[bi][j] += xv[bi] * w[j];
        }
        __syncthreads();
    }

#pragma unroll
    for (int bi = 0; bi < 8; bi++) {
        int b = wv * 8 + bi;
#pragma unroll
        for (int j = 0; j < 4; j++) {
            int o = o0 + lane + 64 * j;
            if (o < O)
                partial[((size_t)s * 32 + b) * O + o] = acc[bi][j];
        }
    }
}

// ---------------------------------------------------------------------------
__global__ __launch_bounds__(256) void reduce_bias(
    const float* __restrict__ partial, const float* __restrict__ bias1,
    const float* __restrict__ bias2, float* __restrict__ Y, int O, int relu,
    int ksplit)
{
    int idx = blockIdx.x * 256 + threadIdx.x;
    if (idx >= 32 * O) return;
    int b = idx / O, o = idx - b * O;
    float s = bias1[o] + (bias2 ? bias2[o] : 0.f);
    for (int k = 0; k < ksplit; k++)
        s += partial[((size_t)k * 32 + b) * O + o];
    Y[idx] = relu ? fmaxf(s, 0.f) : s;
}

// ---------------------------------------------------------------------------
// bf16 helpers
// ---------------------------------------------------------------------------
typedef __attribute__((ext_vector_type(8))) short bf16x8;
typedef __attribute__((ext_vector_type(4))) float f32x4;

__device__ inline uint32_t pkbf(float lo, float hi) {   // 2 f32 -> packed bf16x2 (RNE)
    uint32_t a = __builtin_bit_cast(uint32_t, lo);
    uint32_t b = __builtin_bit_cast(uint32_t, hi);
    a = (a + 0x7FFFu + ((a >> 16) & 1u)) >> 16;
    b = (b + 0x7FFFu + ((b >> 16) & 1u)) & 0xFFFF0000u;
    return a | b;
}
// hi-part pack that also returns the f32 residuals (for hi/lo split-bf16)
__device__ inline uint32_t pk_hi(float a, float b, float& ra, float& rb) {
    uint32_t ua = __builtin_bit_cast(uint32_t, a);
    uint32_t ub = __builtin_bit_cast(uint32_t, b);
    uint32_t ha = (ua + 0x7FFFu + ((ua >> 16) & 1u)) & 0xFFFF0000u;
    uint32_t hb = (ub + 0x7FFFu + ((ub >> 16) & 1u)) & 0xFFFF0000u;
    ra = a - __builtin_bit_cast(float, ha);
    rb = b - __builtin_bit_cast(float, hb);
    return (ha >> 16) | hb;
}

#define MFMA16(a, b, c) __builtin_amdgcn_mfma_f32_16x16x32_bf16(a, b, c, 0, 0, 0)

// ---------------------------------------------------------------------------
// MFMA partial GEMM for the two big layers (w2, wfa).
// partial[s][b][o] = sum_{k in split s} X[b,k]*W[o,k].
// Fragment convention identical to the (absmax-verified) conv kernel:
//   frag elem j <-> k = k0 + 4g + (j&3) + 16*(j>>2); A row / B col = n.
// A = X rows (b), B = W rows (o) streamed straight from HBM (row-major [O][K]
// means the B-frag load pattern == the A-frag load pattern on W). D row=4g+r.
// X enters as hi/lo split bf16 (2 MFMAs) -> ~f16+ precision; W single bf16.
// No LDS, no barriers; occupancy + 1036/882-block grids hide latency.
// Caller guarantees: K1%32==0, kchunk%32==0, O%64==0.
// ---------------------------------------------------------------------------
__global__ __launch_bounds__(256) void gemm32_mfma(
    const float* __restrict__ X1, const float* __restrict__ W1, int K1,
    const float* __restrict__ X2, const float* __restrict__ W2, int K2,
    float* __restrict__ partial, int O, int ksplit)
{
    const int t  = threadIdx.x;
    const int l  = t & 63;
    const int g  = l >> 4;
    const int n  = l & 15;
    const int o0 = blockIdx.x * 64 + (t >> 6) * 16;   // this wave's o-base
    const int s  = blockIdx.y;
    const int kchunk = (K1 + K2) / ksplit;
    const int kbeg   = s * kchunk;
    const int kend   = kbeg + kchunk;

    f32x4 accA, accB;                 // b-half 0 (rows 0-15), b-half 1 (16-31)
#pragma unroll
    for (int r = 0; r < 4; ++r) { accA[r] = 0.f; accB[r] = 0.f; }

#pragma unroll 2
    for (int kc = kbeg; kc < kend; kc += 32) {
        const float* Wr;  const float* Xb;  int kk; int ld;
        if (kc < K1) { Wr = W1; Xb = X1; kk = kc;      ld = K1; }
        else         { Wr = W2; Xb = X2; kk = kc - K1; ld = K2; }

        // ---- B-frag: W row o0+n, k = kk+4g+{0..3}, +16
        const float* wp = Wr + (size_t)(o0 + n) * ld + kk + 4 * g;
        float4 wlo = *(const float4*)wp;
        float4 whi = *(const float4*)(wp + 16);
        union { bf16x8 v; uint32_t u[4]; } wf;
        wf.u[0] = pkbf(wlo.x, wlo.y); wf.u[1] = pkbf(wlo.z, wlo.w);
        wf.u[2] = pkbf(whi.x, whi.y); wf.u[3] = pkbf(whi.z, whi.w);

        // ---- A-frags: X rows 16*bh+n, hi/lo split
#pragma unroll
        for (int bh = 0; bh < 2; ++bh) {
            const float* xp = Xb + (size_t)(16 * bh + n) * ld + kk + 4 * g;
            float4 xa = *(const float4*)xp;
            float4 xb = *(const float4*)(xp + 16);
            float r0, r1, r2, r3, r4, r5, r6, r7;
            union { bf16x8 v; uint32_t u[4]; } xh, xl;
            xh.u[0] = pk_hi(xa.x, xa.y, r0, r1);
            xh.u[1] = pk_hi(xa.z, xa.w, r2, r3);
            xh.u[2] = pk_hi(xb.x, xb.y, r4, r5);
            xh.u[3] = pk_hi(xb.z, xb.w, r6, r7);
            xl.u[0] = pkbf(r0, r1); xl.u[1] = pkbf(r2, r3);
            xl.u[2] = pkbf(r4, r5); xl.u[3] = pkbf(r6, r7);
            if (bh == 0) {
                accA = MFMA16(xh.v, wf.v, accA);
                accA = MFMA16(xl.v, wf.v, accA);
            } else {
                accB = MFMA16(xh.v, wf.v, accB);
                accB = MFMA16(xl.v, wf.v, accB);
            }
        }
    }

    // ---- store: b = 16*bh + 4g + r, o = o0 + n
#pragma unroll
    for (int r = 0; r < 4; ++r) {
        partial[((size_t)s * 32 + (4 * g + r)) * O + o0 + n]      = accA[r];
        partial[((size_t)s * 32 + (16 + 4 * g + r)) * O + o0 + n] = accB[r];
    }
}

// ---------------------------------------------------------------------------
// MFMA conv chain (R8 version — unchanged).
// ---------------------------------------------------------------------------
#define TPW 16   // pixel tiles (16 px) per wave

__global__ __launch_bounds__(256, 3) void conv_mfma(
    const float* __restrict__ x, const float* __restrict__ ks,
    float* __restrict__ out)
{
    const int t  = threadIdx.x;
    const int b  = blockIdx.y;
    const int l  = t & 63;
    const int g  = l >> 4;         // lane group 0..3
    const int n  = l & 15;         // col (pixel-in-tile) / A row offset
    const int wid = blockIdx.x * 4 + (t >> 6);   // wave id in sample, 0..63

    const float* __restrict__ kb = ks + (size_t)b * KT;
    const float* __restrict__ xbase = x + (size_t)b * 524288 + (size_t)(4 * g) * 16384 + n;
    float* __restrict__ obase = out + (size_t)b * 524288 + (size_t)(4 * g) * 16384 + n;

    float e[8];
    auto loadx = [&](int px0) {
        const float* p = xbase + px0;
        e[0] = p[0]; e[1] = p[16384]; e[2] = p[2 * 16384]; e[3] = p[3 * 16384];
        const float* q = p + (size_t)16 * 16384;
        e[4] = q[0]; e[5] = q[16384]; e[6] = q[2 * 16384]; e[7] = q[3 * 16384];
    };
    loadx(wid * TPW * 16);

    auto loadA = [&](const float* W, int ldw, int row0, int k0) -> bf16x8 {
        const float* p = W + (size_t)(row0 + n) * ldw + k0 + 4 * g;
        float4 lo = *(const float4*)p;
        float4 hi = *(const float4*)(p + 16);
        union { bf16x8 v; uint32_t u[4]; } r;
        r.u[0] = pkbf(lo.x, lo.y);
        r.u[1] = pkbf(lo.z, lo.w);
        r.u[2] = pkbf(hi.x, hi.y);
        r.u[3] = pkbf(hi.z, hi.w);
        return r.v;
    };
    auto loadBias = [&](int off) -> f32x4 {
        float4 v = *(const float4*)&kb[off + 4 * g];
        f32x4 r; r[0] = v.x; r[1] = v.y; r[2] = v.z; r[3] = v.w;
        return r;
    };

    bf16x8 ain[4], amid[4][2], aout[2][2], ashort[2];
#pragma unroll
    for (int rt = 0; rt < 4; ++rt) ain[rt] = loadA(kb, 32, 16 * rt, 0);
#pragma unroll
    for (int ot = 0; ot < 4; ++ot)
#pragma unroll
        for (int kf = 0; kf < 2; ++kf) amid[ot][kf] = loadA(kb + 2048, 64, 16 * ot, 32 * kf);
#pragma unroll
    for (int ot = 0; ot < 2; ++ot)
#pragma unroll
        for (int kf = 0; kf < 2; ++kf) aout[ot][kf] = loadA(kb + 6144, 64, 16 * ot, 32 * kf);
#pragma unroll
    for (int ot = 0; ot < 2; ++ot) ashort[ot] = loadA(kb + 8192, 32, 16 * ot, 0);

    f32x4 bin[4], bmid[4], bos[2];
#pragma unroll
    for (int rt = 0; rt < 4; ++rt) bin[rt] = loadBias(9216 + 16 * rt);
#pragma unroll
    for (int ot = 0; ot < 4; ++ot) bmid[ot] = loadBias(9280 + 16 * ot);
#pragma unroll
    for (int ot = 0; ot < 2; ++ot) {
        f32x4 a = loadBias(9344 + 16 * ot);   // b_out
        f32x4 c = loadBias(9376 + 16 * ot);   // b_short
#pragma unroll
        for (int r = 0; r < 4; ++r) a[r] += c[r];
        bos[ot] = a;
    }

#pragma unroll 1
    for (int it = 0; it < TPW; ++it) {
        const int px0 = (wid * TPW + it) * 16;

        union { bf16x8 v; uint32_t u[4]; } bx;
        bx.u[0] = pkbf(e[0], e[1]); bx.u[1] = pkbf(e[2], e[3]);
        bx.u[2] = pkbf(e[4], e[5]); bx.u[3] = pkbf(e[6], e[7]);

        if (it + 1 < TPW) loadx(px0 + 16);   // flies under the MFMA chain

        f32x4 h[4];
#pragma unroll
        for (int rt = 0; rt < 4; ++rt) {
            f32x4 acc = MFMA16(ain[rt], bx.v, bin[rt]);
#pragma unroll
            for (int r = 0; r < 4; ++r) acc[r] = fmaxf(acc[r], 0.f);
            h[rt] = acc;
        }
        union { bf16x8 v; uint32_t u[4]; } hb0, hb1;
        hb0.u[0] = pkbf(h[0][0], h[0][1]); hb0.u[1] = pkbf(h[0][2], h[0][3]);
        hb0.u[2] = pkbf(h[1][0], h[1][1]); hb0.u[3] = pkbf(h[1][2], h[1][3]);
        hb1.u[0] = pkbf(h[2][0], h[2][1]); hb1.u[1] = pkbf(h[2][2], h[2][3]);
        hb1.u[2] = pkbf(h[3][0], h[3][1]); hb1.u[3] = pkbf(h[3][2], h[3][3]);

        f32x4 m[4];
#pragma unroll
        for (int ot = 0; ot < 4; ++ot) {
            f32x4 acc = MFMA16(amid[ot][0], hb0.v, bmid[ot]);
            acc = MFMA16(amid[ot][1], hb1.v, acc);
#pragma unroll
            for (int r = 0; r < 4; ++r) acc[r] = fmaxf(acc[r], 0.f);
            m[ot] = acc;
        }
        union { bf16x8 v; uint32_t u[4]; } mb0, mb1;
        mb0.u[0] = pkbf(m[0][0], m[0][1]); mb0.u[1] = pkbf(m[0][2], m[0][3]);
        mb0.u[2] = pkbf(m[1][0], m[1][1]); mb0.u[3] = pkbf(m[1][2], m[1][3]);
        mb1.u[0] = pkbf(m[2][0], m[2][1]); mb1.u[1] = pkbf(m[2][2], m[2][3]);
        mb1.u[2] = pkbf(m[3][0], m[3][1]); mb1.u[3] = pkbf(m[3][2], m[3][3]);

#pragma unroll
        for (int ot = 0; ot < 2; ++ot) {
            f32x4 acc = MFMA16(ashort[ot], bx.v, bos[ot]);
            acc = MFMA16(aout[ot][0], mb0.v, acc);
            acc = MFMA16(aout[ot][1], mb1.v, acc);
            float* po = obase + (size_t)(16 * ot) * 16384 + px0;
            po[0]         = acc[0];
            po[16384]     = acc[1];
            po[2 * 16384] = acc[2];
            po[3 * 16384] = acc[3];
        }
    }
}

// ---------------------------------------------------------------------------
extern "C" void kernel_launch(void* const* d_in, const int* in_sizes, int n_in,
                              void* d_out, int out_size, void* d_ws, size_t ws_size,
                              hipStream_t stream)
{
    const float* x   = (const float*)d_in[0];
    const float* lat = (const float*)d_in[1];
    const float* w0  = (const float*)d_in[2];
    const float* b0  = (const float*)d_in[3];
    const float* w1a = (const float*)d_in[4];
    const float* b1a = (const float*)d_in[5];
    const float* w1b = (const float*)d_in[6];
    const float* b1b = (const float*)d_in[7];
    const float* w1s = (const float*)d_in[8];
    const float* b1s = (const float*)d_in[9];
    const float* w2a = (const float*)d_in[10];
    const float* b2a = (const float*)d_in[11];
    const float* w2b = (const float*)d_in[12];
    const float* b2b = (const float*)d_in[13];
    const float* w2s = (const float*)d_in[14];
    const float* b2s = (const float*)d_in[15];
    const float* wfa = (const float*)d_in[16];
    const float* bfa = (const float*)d_in[17];

    // intermediates in d_ws (~2.8 MB)
    float* ws  = (float*)d_ws;
    float* h0  = ws;               // 32*512
    float* t1  = ws + 16384;       // 32*1024
    float* h1  = ws + 49152;       // 32*512
    float* t2  = ws + 65536;       // 32*1024
    float* h2  = ws + 98304;       // 32*9408
    float* ksb = ws + 399360;      // 32*9408
    // K-split partials live in d_out (<=8.4 MB < 64 MB); conv overwrites at end.
    float* pbuf = (float*)d_out;

    dim3 blk(256);
    auto rg = [](int O) { return dim3((unsigned)((32 * O + 255) / 256)); };

    // small chain (f32, R5-exact)
    gemm32_partial<<<dim3(2, 32), blk, 0, stream>>>(lat, w0, 512, nullptr, nullptr, 0, pbuf, 512, 32);
    reduce_bias<<<rg(512), blk, 0, stream>>>(pbuf, b0, nullptr, h0, 512, 0, 32);
    gemm32_partial<<<dim3(4, 32), blk, 0, stream>>>(h0, w1a, 512, nullptr, nullptr, 0, pbuf, 1024, 32);
    reduce_bias<<<rg(1024), blk, 0, stream>>>(pbuf, b1a, nullptr, t1, 1024, 1, 32);
    gemm32_partial<<<dim3(2, 32), blk, 0, stream>>>(h0, w1s, 512, t1, w1b, 1024, pbuf, 512, 32);
    reduce_bias<<<rg(512), blk, 0, stream>>>(pbuf, b1s, b1b, h1, 512, 0, 32);
    gemm32_partial<<<dim3(4, 32), blk, 0, stream>>>(h1, w2a, 512, nullptr, nullptr, 0, pbuf, 1024, 32);
    reduce_bias<<<rg(1024), blk, 0, stream>>>(pbuf, b2a, nullptr, t2, 1024, 1, 32);

    // h2 = h1 @ w2s.T + b2s + t2 @ w2b.T + b2b   (MFMA, ksplit 6, 882 blocks)
    gemm32_mfma<<<dim3(147, 6), blk, 0, stream>>>(h1, w2s, 512, t2, w2b, 1024, pbuf, KT, 6);
    reduce_bias<<<rg(KT), blk, 0, stream>>>(pbuf, b2s, b2b, h2, KT, 0, 6);
    // ks = h2 @ wfa.T + bfa                      (MFMA, ksplit 7, 1029 blocks)
    gemm32_mfma<<<dim3(147, 7), blk, 0, stream>>>(h2, wfa, KT, nullptr, nullptr, 0, pbuf, KT, 7);
    reduce_bias<<<rg(KT), blk, 0, stream>>>(pbuf, bfa, nullptr, ksb, KT, 0, 7);

    // MFMA conv chain: grid (16 px-blocks, 32 samples), 4 waves/block, 16 tiles/wave
    conv_mfma<<<dim3(16, 32), blk, 0, stream>>>(x, ksb, (float*)d_out);
}